// Round 15
// baseline (110.031 us; speedup 1.0000x reference)
//
#include <hip/hip_runtime.h>

#define SHIFT 10.0f
#define CAP 64      // padded CSR slots per node (max deg 63 + implicit self-loop)
#define NXCD 8
#define BSH 7       // log2(bucket size): 128 nodes per bucket
#define CAPB 3072   // intermediate slots per 128-node bucket (mean 2046 + ~20 sigma)

typedef __attribute__((ext_vector_type(8))) short bf16x8;
typedef __attribute__((ext_vector_type(4))) float f32x4;
typedef _Float16 half2v __attribute__((ext_vector_type(2)));

__device__ inline uint16_t bf16r(float f) {
    uint32_t u = __float_as_uint(f);
    return (uint16_t)((u + 0x7FFFu + ((u >> 16) & 1u)) >> 16);
}
__device__ inline float bf2f(uint16_t h) {
    return __uint_as_float(((uint32_t)h) << 16);
}
__device__ inline uint32_t pack_bf16x2(float lo, float hi) {
    return (uint32_t)bf16r(lo) | ((uint32_t)bf16r(hi) << 16);
}
__device__ inline uint32_t pack_f16x2(float lo, float hi) {
    uint16_t a = __builtin_bit_cast(uint16_t, (_Float16)lo);
    uint16_t b = __builtin_bit_cast(uint16_t, (_Float16)hi);
    return (uint32_t)a | ((uint32_t)b << 16);
}
__device__ inline half2v as_h2(uint32_t u) {
    return __builtin_bit_cast(half2v, u);
}

// -------- fused prep (blocks 0..31) || bin_a (blocks 32..) ------------------
// R14's LDS bucket-sort bin_a — UNCHANGED.
#define ABSZ 512
#define AEPT 16
#define PREP_BLKS 32
__global__ __launch_bounds__(ABSZ) void prep_bin(
    const float* __restrict__ Wq, const float* __restrict__ Wk,
    const float* __restrict__ Wv, uint32_t* __restrict__ Wh32,
    uint32_t* __restrict__ Wl32,
    const int* __restrict__ row, const int* __restrict__ col,
    int* __restrict__ bucketCursor, uint32_t* __restrict__ inter, int E)
{
    if (blockIdx.x < PREP_BLKS) {
        int t = blockIdx.x * ABSZ + threadIdx.x;   // [0, 16384)
        int c = t >> 6;
        int k2 = t & 63;
        float f0, f1;
        if (c < 64)       { f0 = Wq[(2 * k2) * 64 + c];          f1 = Wq[(2 * k2 + 1) * 64 + c]; }
        else if (c < 128) { f0 = Wk[(2 * k2) * 64 + (c - 64)];   f1 = Wk[(2 * k2 + 1) * 64 + (c - 64)]; }
        else              { f0 = Wv[(2 * k2) * 128 + (c - 128)]; f1 = Wv[(2 * k2 + 1) * 128 + (c - 128)]; }
        uint16_t h0 = bf16r(f0), h1 = bf16r(f1);
        uint16_t l0 = bf16r(f0 - bf2f(h0)), l1 = bf16r(f1 - bf2f(h1));
        Wh32[t] = (uint32_t)h0 | ((uint32_t)h1 << 16);
        Wl32[t] = (uint32_t)l0 | ((uint32_t)l1 << 16);
        return;
    }

    __shared__ int hist[512];
    __shared__ int scanI[512];     // inclusive scan workspace
    __shared__ int basebuf[512];
    __shared__ uint32_t edges[ABSZ * AEPT];   // 32 KB bucket-sorted edges

    const int t = threadIdx.x;
    hist[t] = 0;
    __syncthreads();

    const int base0 = (blockIdx.x - PREP_BLKS) * ABSZ * AEPT;
    const int total = min(E - base0, ABSZ * AEPT);
    uint32_t pk[AEPT];
    int rk[AEPT];
#pragma unroll
    for (int k = 0; k < AEPT; ++k) {
        int e = base0 + k * ABSZ + t;          // coalesced per k-slice
        if (e < E) {
            int r = row[e];
            int c = col[e];
            pk[k] = ((uint32_t)r << 16) | (uint32_t)c;   // N,E indices < 65536
            rk[k] = atomicAdd(&hist[r >> BSH], 1);       // LDS atomic: in-block rank
        } else rk[k] = -1;
    }
    __syncthreads();

    // exclusive scan of hist (Hillis-Steele inclusive, then subtract)
    scanI[t] = hist[t];
    __syncthreads();
#pragma unroll
    for (int off = 1; off < 512; off <<= 1) {
        int v = (t >= off) ? scanI[t - off] : 0;
        __syncthreads();
        scanI[t] += v;
        __syncthreads();
    }
    // global reservation per bucket
    {
        int h = hist[t];
        basebuf[t] = h ? atomicAdd(&bucketCursor[t], h) : 0;   // only global atomic
    }
    __syncthreads();

    // place edges into LDS in bucket-sorted order
#pragma unroll
    for (int k = 0; k < AEPT; ++k) {
        if (rk[k] >= 0) {
            int b = (int)(pk[k] >> (16 + BSH));
            edges[scanI[b] - hist[b] + rk[k]] = pk[k];
        }
    }
    __syncthreads();

    // linear sweep: consecutive i -> same bucket -> contiguous global runs
    for (int i = t; i < total; i += ABSZ) {
        uint32_t u = edges[i];
        int b = (int)(u >> (16 + BSH));
        int gpos = basebuf[b] + (i - (scanI[b] - hist[b]));
        if (gpos < CAPB)
            inter[(size_t)b * CAPB + gpos] = u;
    }
}

// -------- fused: bin_b (blockIdx < NB) co-resident with nl_qkv --------------
// R15: x staged as SINGLE bf16 (Al dropped). W stays hi/lo. MFMA terms:
// ah*bh + ah*bl (32 MFMAs vs 48), A-side LDS reads halve, LDS 34.5->17.9KB.
// Precision cost: x-quantization propagates ~0.007 to QKV, ~0.03 to scores.
// Diagnostic: work-proportional NL -> ~35us; fixed-stall -> unchanged.
__global__ __launch_bounds__(256) void fused_nlb(
    const uint32_t* __restrict__ inter, const int* __restrict__ bucketCursor,
    uint16_t* __restrict__ csr, int* __restrict__ deg,
    const float* __restrict__ x,
    const uint16_t* __restrict__ Wh, const uint16_t* __restrict__ Wl,
    const float* __restrict__ bq, const float* __restrict__ bk,
    float* __restrict__ Qn, uint32_t* __restrict__ Kh, uint32_t* __restrict__ Vh,
    int N, int NB)
{
    __shared__ uint16_t Ah[64][136];
    __shared__ int cnt[128];

    if (blockIdx.x < NB) {
        // ---- bin_b path ----
        const int b = blockIdx.x;
        const int t = threadIdx.x;
        if (t < 128) cnt[t] = 0;
        __syncthreads();

        const int count = min(bucketCursor[b], CAPB);
        const uint32_t* src = inter + (size_t)b * CAPB;
        for (int i = t; i < count; i += 256) {
            uint32_t u = src[i];
            int r = (int)(u >> 16);
            int pos = atomicAdd(&cnt[r & 127], 1);          // LDS atomic
            if (pos < CAP - 1)
                csr[(size_t)r * CAP + pos] = (uint16_t)(u & 0xFFFFu);
        }
        __syncthreads();

        const int node = (b << BSH) + t;
        if (t < 128 && node < N) deg[node] = min(cnt[t], CAP - 1);
        return;
    }

    // ---- node-linear path: 64 nodes per block ----
    const int tid = threadIdx.x;
    const int lane = tid & 63;
    const int wv = tid >> 6;
    const int block0 = (blockIdx.x - NB) * 64;
    if (block0 >= N) return;

    float4 v[8];
#pragma unroll
    for (int i = 0; i < 8; ++i) {
        int idx = tid + i * 256;      // float4 index
        int node = idx >> 5;
        int c4 = idx & 31;
        v[i] = make_float4(0.f, 0.f, 0.f, 0.f);
        if (block0 + node < N)
            v[i] = reinterpret_cast<const float4*>(x + (size_t)(block0 + node) * 128)[c4];
    }
#pragma unroll
    for (int i = 0; i < 8; ++i) {
        int idx = tid + i * 256;
        int node = idx >> 5;
        int c4 = idx & 31;
        uint2 uh;
        uh.x = pack_bf16x2(v[i].x, v[i].y);
        uh.y = pack_bf16x2(v[i].z, v[i].w);
        *reinterpret_cast<uint2*>(&Ah[node][c4 * 4]) = uh;
    }
    __syncthreads();

    f32x4 acc[4][4] = {};   // [rf][cf]
#pragma unroll
    for (int ks = 0; ks < 4; ++ks) {
        bf16x8 bh[4], bl[4];
#pragma unroll
        for (int cf = 0; cf < 4; ++cf) {
            size_t off = (size_t)(wv * 64 + cf * 16 + (lane & 15)) * 128
                         + ks * 32 + (lane >> 4) * 8;
            bh[cf] = *reinterpret_cast<const bf16x8*>(Wh + off);
            bl[cf] = *reinterpret_cast<const bf16x8*>(Wl + off);
        }
#pragma unroll
        for (int rf = 0; rf < 4; ++rf) {
            bf16x8 ah = *reinterpret_cast<const bf16x8*>(
                &Ah[rf * 16 + (lane & 15)][ks * 32 + (lane >> 4) * 8]);
#pragma unroll
            for (int cf = 0; cf < 4; ++cf)
                acc[rf][cf] = __builtin_amdgcn_mfma_f32_16x16x32_bf16(
                    ah, bh[cf], acc[rf][cf], 0, 0, 0);
#pragma unroll
            for (int cf = 0; cf < 4; ++cf)
                acc[rf][cf] = __builtin_amdgcn_mfma_f32_16x16x32_bf16(
                    ah, bl[cf], acc[rf][cf], 0, 0, 0);
        }
    }

    // epilogue: C layout col = lane&15, row = (lane>>4)*4 + r
#pragma unroll
    for (int rf = 0; rf < 4; ++rf) {
#pragma unroll
        for (int cf = 0; cf < 4; ++cf) {
            const int ocol = wv * 64 + cf * 16 + (lane & 15);
#pragma unroll
            for (int r = 0; r < 4; ++r) {
                const int orow = rf * 16 + (lane >> 4) * 4 + r;
                const int node = block0 + orow;
                float v2 = acc[rf][cf][r];
                if (wv == 0) {
                    v2 = fmaxf(v2 + bq[ocol], 0.f);
                    if (node < N) Qn[(size_t)node * 64 + ocol] = v2;
                } else if (wv == 1) {
                    const int ck = ocol - 64;
                    v2 = fmaxf(v2 + bk[ck], 0.f);
                    float vp = __shfl_xor(v2, 1);
                    if (node < N && !(lane & 1))
                        Kh[(size_t)node * 32 + (ck >> 1)] = pack_f16x2(v2, vp);
                } else {
                    const int cv = ocol - 128;
                    float vp = __shfl_xor(v2, 1);
                    if (node < N && !(lane & 1))
                        Vh[(size_t)node * 64 + (cv >> 1)] = pack_bf16x2(v2, vp);
                }
            }
        }
    }
}

// -------- aggregation: f16 Q/K via v_dot2, byte-offset gathers --------------
// R13's agg6 — UNCHANGED.
__global__ __launch_bounds__(256) void agg6(
    const int* __restrict__ deg_, const uint16_t* __restrict__ csr,
    const float* __restrict__ Qn, const uint32_t* __restrict__ Kh,
    const uint32_t* __restrict__ Vh, const float* __restrict__ bias,
    float* __restrict__ out, int N)
{
    __shared__ uint32_t qs[4][32];
    __shared__ float es[4][8][36];
    __shared__ int   cis[4][32];   // V row BYTE offsets (c << 8)

    const int wv = threadIdx.x >> 6;
    const int lane = threadIdx.x & 63;

    const int xcd = blockIdx.x & (NXCD - 1);
    const int nslice = (N + NXCD - 1) / NXCD;
    const int ln = (blockIdx.x >> 3) * 4 + wv;
    if (ln >= nslice) return;
    const int n = xcd * nslice + ln;
    if (n >= N) return;

    const int deg = min(deg_[n], CAP - 1);
    const int tot = deg + 1;   // + self-loop

    if (lane < 32) {
        float2 qq = reinterpret_cast<const float2*>(Qn + (size_t)n * 64)[lane];
        qs[wv][lane] = pack_f16x2(qq.x, qq.y);
    }
    __builtin_amdgcn_wave_barrier();

    const int e2 = lane >> 1;      // phase-A edge 0..31
    const int half = lane & 1;     // K half (heads 4*half..4*half+3)
    const int hrow = lane >> 3;    // phase-B head of feature pair 2*lane
    const float* esrow = &es[wv][hrow][0];
    const char* Kb = (const char*)Kh;
    const char* Vb = (const char*)Vh;
    const int lane4 = lane << 2;

    float accx = 0.f, accy = 0.f, accL = 0.f;

    for (int base = 0; base < tot; base += 32) {
        const int nn = min(32, tot - base);
        const int idxe = base + e2;
        const bool valide = (idxe < tot);
        int c = n;
        if (valide && idxe < deg) c = (int)csr[(size_t)n * CAP + idxe];
        if (!valide) c = 0;
        cis[wv][e2] = c << 8;   // both halves write same value

        const uint32_t koff = ((uint32_t)c << 7) + ((uint32_t)half << 6);
        const uint32_t* q16 = &qs[wv][half * 16];
#pragma unroll
        for (int hh = 0; hh < 4; ++hh) {
            uint4 kv = *reinterpret_cast<const uint4*>(Kb + koff + hh * 16);
            const uint32_t* q4 = q16 + hh * 4;
            float s = 0.f;
            s = __builtin_amdgcn_fdot2(as_h2(kv.x), as_h2(q4[0]), s, false);
            s = __builtin_amdgcn_fdot2(as_h2(kv.y), as_h2(q4[1]), s, false);
            s = __builtin_amdgcn_fdot2(as_h2(kv.z), as_h2(q4[2]), s, false);
            s = __builtin_amdgcn_fdot2(as_h2(kv.w), as_h2(q4[3]), s, false);
            es[wv][half * 4 + hh][e2] = valide ? __expf(s - SHIFT) : 0.f;
        }
        __builtin_amdgcn_wave_barrier();

        const int nn4 = (nn + 3) & ~3;
        for (int i = 0; i < nn4; i += 4) {
            int4 c4 = *reinterpret_cast<const int4*>(&cis[wv][i]);
            float4 e4 = *reinterpret_cast<const float4*>(&esrow[i]);
            uint32_t u0 = *reinterpret_cast<const uint32_t*>(Vb + (uint32_t)(c4.x + lane4));
            uint32_t u1 = *reinterpret_cast<const uint32_t*>(Vb + (uint32_t)(c4.y + lane4));
            uint32_t u2 = *reinterpret_cast<const uint32_t*>(Vb + (uint32_t)(c4.z + lane4));
            uint32_t u3 = *reinterpret_cast<const uint32_t*>(Vb + (uint32_t)(c4.w + lane4));
            accx += e4.x * __uint_as_float(u0 << 16);
            accy += e4.x * __uint_as_float(u0 & 0xFFFF0000u);
            accL += e4.x;
            accx += e4.y * __uint_as_float(u1 << 16);
            accy += e4.y * __uint_as_float(u1 & 0xFFFF0000u);
            accL += e4.y;
            accx += e4.z * __uint_as_float(u2 << 16);
            accy += e4.z * __uint_as_float(u2 & 0xFFFF0000u);
            accL += e4.z;
            accx += e4.w * __uint_as_float(u3 << 16);
            accy += e4.w * __uint_as_float(u3 & 0xFFFF0000u);
            accL += e4.w;
        }
        __builtin_amdgcn_wave_barrier();
    }

    float2 b = reinterpret_cast<const float2*>(bias)[lane];
    float inv = 1.0f / accL;
    float2 o;
    o.x = accx * inv + b.x;
    o.y = accy * inv + b.y;
    reinterpret_cast<float2*>(out)[(size_t)n * 64 + lane] = o;
}

extern "C" void kernel_launch(void* const* d_in, const int* in_sizes, int n_in,
                              void* d_out, int out_size, void* d_ws, size_t ws_size,
                              hipStream_t stream) {
    const float* x    = (const float*)d_in[0];
    const int*   ei   = (const int*)d_in[1];
    const float* Wq   = (const float*)d_in[2];
    const float* bq   = (const float*)d_in[3];
    const float* Wk   = (const float*)d_in[4];
    const float* bk   = (const float*)d_in[5];
    const float* Wv   = (const float*)d_in[6];
    const float* bias = (const float*)d_in[7];
    float* out = (float*)d_out;

    const int N = in_sizes[0] / 128;
    const int E = in_sizes[1] / 2;
    const int* row = ei;
    const int* col = ei + E;
    const int NB = (N + (1 << BSH) - 1) >> BSH;   // 128-node buckets

    // workspace layout (~44MB); csr u16 (N<=65535)
    float*    Qn     = (float*)d_ws;                       // N*64 f32
    uint32_t* Kh     = (uint32_t*)(Qn + (size_t)N * 64);   // N*32 u32 (f16x2)
    uint32_t* Vh     = Kh + (size_t)N * 32;                // N*64 u32 (bf16x2)
    uint32_t* Wh32   = Vh + (size_t)N * 64;                // 16384 u32
    uint32_t* Wl32   = Wh32 + 16384;                       // 16384 u32
    int*      deg    = (int*)(Wl32 + 16384);               // N
    int*      bcur   = deg + N;                            // 512
    uint32_t* inter  = (uint32_t*)(bcur + 512);            // NB*CAPB u32
    uint16_t* csr    = (uint16_t*)(inter + (size_t)NB * CAPB);  // N*CAP u16

    const int nslice = (N + NXCD - 1) / NXCD;
    const int agg_grid = ((nslice + 3) / 4) * NXCD;
    const int nl_grid = (N + 63) / 64;
    const int binA_grid = (E + ABSZ * AEPT - 1) / (ABSZ * AEPT);

    hipMemsetAsync(bcur, 0, 512 * sizeof(int), stream);
    prep_bin<<<PREP_BLKS + binA_grid, ABSZ, 0, stream>>>(
        Wq, Wk, Wv, Wh32, Wl32, row, col, bcur, inter, E);
    fused_nlb<<<NB + nl_grid, 256, 0, stream>>>(
        inter, bcur, csr, deg,
        x, (const uint16_t*)Wh32, (const uint16_t*)Wl32, bq, bk,
        Qn, Kh, Vh, N, NB);
    agg6<<<agg_grid, 256, 0, stream>>>(
        deg, csr, Qn, Kh, Vh, bias, out, N);
}

// Round 16
// 105.151 us; speedup vs baseline: 1.0464x; 1.0464x over previous
//
#include <hip/hip_runtime.h>

#define SHIFT 10.0f
#define CAP 64      // padded CSR slots per node (max deg 63 + implicit self-loop)
#define NXCD 8
#define BSH 7       // log2(bucket size): 128 nodes per bucket
#define CAPB 3072   // intermediate slots per 128-node bucket (mean 2046 + ~20 sigma)

typedef __attribute__((ext_vector_type(8))) short bf16x8;
typedef __attribute__((ext_vector_type(4))) float f32x4;
typedef _Float16 half2v __attribute__((ext_vector_type(2)));

__device__ inline uint16_t bf16r(float f) {
    uint32_t u = __float_as_uint(f);
    return (uint16_t)((u + 0x7FFFu + ((u >> 16) & 1u)) >> 16);
}
__device__ inline float bf2f(uint16_t h) {
    return __uint_as_float(((uint32_t)h) << 16);
}
__device__ inline uint32_t pack_bf16x2(float lo, float hi) {
    return (uint32_t)bf16r(lo) | ((uint32_t)bf16r(hi) << 16);
}
__device__ inline uint32_t pack_f16x2(float lo, float hi) {
    uint16_t a = __builtin_bit_cast(uint16_t, (_Float16)lo);
    uint16_t b = __builtin_bit_cast(uint16_t, (_Float16)hi);
    return (uint32_t)a | ((uint32_t)b << 16);
}
__device__ inline half2v as_h2(uint32_t u) {
    return __builtin_bit_cast(half2v, u);
}

// -------- fused prep (blocks 0..31) || bin_a (blocks 32..) ------------------
// R14's LDS bucket-sort bin_a.
#define ABSZ 512
#define AEPT 16
#define PREP_BLKS 32
__global__ __launch_bounds__(ABSZ) void prep_bin(
    const float* __restrict__ Wq, const float* __restrict__ Wk,
    const float* __restrict__ Wv, uint32_t* __restrict__ Wh32,
    uint32_t* __restrict__ Wl32,
    const int* __restrict__ row, const int* __restrict__ col,
    int* __restrict__ bucketCursor, uint32_t* __restrict__ inter, int E)
{
    if (blockIdx.x < PREP_BLKS) {
        int t = blockIdx.x * ABSZ + threadIdx.x;   // [0, 16384)
        int c = t >> 6;
        int k2 = t & 63;
        float f0, f1;
        if (c < 64)       { f0 = Wq[(2 * k2) * 64 + c];          f1 = Wq[(2 * k2 + 1) * 64 + c]; }
        else if (c < 128) { f0 = Wk[(2 * k2) * 64 + (c - 64)];   f1 = Wk[(2 * k2 + 1) * 64 + (c - 64)]; }
        else              { f0 = Wv[(2 * k2) * 128 + (c - 128)]; f1 = Wv[(2 * k2 + 1) * 128 + (c - 128)]; }
        uint16_t h0 = bf16r(f0), h1 = bf16r(f1);
        uint16_t l0 = bf16r(f0 - bf2f(h0)), l1 = bf16r(f1 - bf2f(h1));
        Wh32[t] = (uint32_t)h0 | ((uint32_t)h1 << 16);
        Wl32[t] = (uint32_t)l0 | ((uint32_t)l1 << 16);
        return;
    }

    __shared__ int hist[512];
    __shared__ int scanI[512];     // inclusive scan workspace
    __shared__ int basebuf[512];
    __shared__ uint32_t edges[ABSZ * AEPT];   // 32 KB bucket-sorted edges

    const int t = threadIdx.x;
    hist[t] = 0;
    __syncthreads();

    const int base0 = (blockIdx.x - PREP_BLKS) * ABSZ * AEPT;
    const int total = min(E - base0, ABSZ * AEPT);
    uint32_t pk[AEPT];
    int rk[AEPT];
#pragma unroll
    for (int k = 0; k < AEPT; ++k) {
        int e = base0 + k * ABSZ + t;          // coalesced per k-slice
        if (e < E) {
            int r = row[e];
            int c = col[e];
            pk[k] = ((uint32_t)r << 16) | (uint32_t)c;   // N,E indices < 65536
            rk[k] = atomicAdd(&hist[r >> BSH], 1);       // LDS atomic: in-block rank
        } else rk[k] = -1;
    }
    __syncthreads();

    // exclusive scan of hist (Hillis-Steele inclusive, then subtract)
    scanI[t] = hist[t];
    __syncthreads();
#pragma unroll
    for (int off = 1; off < 512; off <<= 1) {
        int v = (t >= off) ? scanI[t - off] : 0;
        __syncthreads();
        scanI[t] += v;
        __syncthreads();
    }
    // global reservation per bucket
    {
        int h = hist[t];
        basebuf[t] = h ? atomicAdd(&bucketCursor[t], h) : 0;   // only global atomic
    }
    __syncthreads();

    // place edges into LDS in bucket-sorted order
#pragma unroll
    for (int k = 0; k < AEPT; ++k) {
        if (rk[k] >= 0) {
            int b = (int)(pk[k] >> (16 + BSH));
            edges[scanI[b] - hist[b] + rk[k]] = pk[k];
        }
    }
    __syncthreads();

    // linear sweep: consecutive i -> same bucket -> contiguous global runs
    for (int i = t; i < total; i += ABSZ) {
        uint32_t u = edges[i];
        int b = (int)(u >> (16 + BSH));
        int gpos = basebuf[b] + (i - (scanI[b] - hist[b]));
        if (gpos < CAPB)
            inter[(size_t)b * CAPB + gpos] = u;
    }
}

// -------- fused: bin_b (blockIdx < NB) co-resident with nl_qkv --------------
// R13/R14's exact structure (best measured: fused_nlb 46.5-47.6us).
__global__ __launch_bounds__(256) void fused_nlb(
    const uint32_t* __restrict__ inter, const int* __restrict__ bucketCursor,
    uint16_t* __restrict__ csr, int* __restrict__ deg,
    const float* __restrict__ x,
    const uint16_t* __restrict__ Wh, const uint16_t* __restrict__ Wl,
    const float* __restrict__ bq, const float* __restrict__ bk,
    float* __restrict__ Qn, uint32_t* __restrict__ Kh, uint32_t* __restrict__ Vh,
    int N, int NB)
{
    __shared__ uint16_t Ah[64][136];
    __shared__ uint16_t Al[64][136];
    __shared__ int cnt[128];

    if (blockIdx.x < NB) {
        // ---- bin_b path ----
        const int b = blockIdx.x;
        const int t = threadIdx.x;
        if (t < 128) cnt[t] = 0;
        __syncthreads();

        const int count = min(bucketCursor[b], CAPB);
        const uint32_t* src = inter + (size_t)b * CAPB;
        for (int i = t; i < count; i += 256) {
            uint32_t u = src[i];
            int r = (int)(u >> 16);
            int pos = atomicAdd(&cnt[r & 127], 1);          // LDS atomic
            if (pos < CAP - 1)
                csr[(size_t)r * CAP + pos] = (uint16_t)(u & 0xFFFFu);
        }
        __syncthreads();

        const int node = (b << BSH) + t;
        if (t < 128 && node < N) deg[node] = min(cnt[t], CAP - 1);
        return;
    }

    // ---- node-linear path: 64 nodes per block ----
    const int tid = threadIdx.x;
    const int lane = tid & 63;
    const int wv = tid >> 6;
    const int block0 = (blockIdx.x - NB) * 64;
    if (block0 >= N) return;

    float4 v[8];
#pragma unroll
    for (int i = 0; i < 8; ++i) {
        int idx = tid + i * 256;      // float4 index
        int node = idx >> 5;
        int c4 = idx & 31;
        v[i] = make_float4(0.f, 0.f, 0.f, 0.f);
        if (block0 + node < N)
            v[i] = reinterpret_cast<const float4*>(x + (size_t)(block0 + node) * 128)[c4];
    }
#pragma unroll
    for (int i = 0; i < 8; ++i) {
        int idx = tid + i * 256;
        int node = idx >> 5;
        int c4 = idx & 31;
        uint16_t hx = bf16r(v[i].x), hy = bf16r(v[i].y), hz = bf16r(v[i].z), hw = bf16r(v[i].w);
        uint2 uh, ul;
        uh.x = (uint32_t)hx | ((uint32_t)hy << 16);
        uh.y = (uint32_t)hz | ((uint32_t)hw << 16);
        ul.x = (uint32_t)bf16r(v[i].x - bf2f(hx)) | ((uint32_t)bf16r(v[i].y - bf2f(hy)) << 16);
        ul.y = (uint32_t)bf16r(v[i].z - bf2f(hz)) | ((uint32_t)bf16r(v[i].w - bf2f(hw)) << 16);
        *reinterpret_cast<uint2*>(&Ah[node][c4 * 4]) = uh;
        *reinterpret_cast<uint2*>(&Al[node][c4 * 4]) = ul;
    }
    __syncthreads();

    f32x4 acc[4][4] = {};   // [rf][cf]
#pragma unroll
    for (int ks = 0; ks < 4; ++ks) {
        bf16x8 bh[4], bl[4];
#pragma unroll
        for (int cf = 0; cf < 4; ++cf) {
            size_t off = (size_t)(wv * 64 + cf * 16 + (lane & 15)) * 128
                         + ks * 32 + (lane >> 4) * 8;
            bh[cf] = *reinterpret_cast<const bf16x8*>(Wh + off);
            bl[cf] = *reinterpret_cast<const bf16x8*>(Wl + off);
        }
#pragma unroll
        for (int rf = 0; rf < 4; ++rf) {
            bf16x8 ah = *reinterpret_cast<const bf16x8*>(
                &Ah[rf * 16 + (lane & 15)][ks * 32 + (lane >> 4) * 8]);
            bf16x8 al = *reinterpret_cast<const bf16x8*>(
                &Al[rf * 16 + (lane & 15)][ks * 32 + (lane >> 4) * 8]);
#pragma unroll
            for (int cf = 0; cf < 4; ++cf)
                acc[rf][cf] = __builtin_amdgcn_mfma_f32_16x16x32_bf16(
                    ah, bh[cf], acc[rf][cf], 0, 0, 0);
#pragma unroll
            for (int cf = 0; cf < 4; ++cf)
                acc[rf][cf] = __builtin_amdgcn_mfma_f32_16x16x32_bf16(
                    ah, bl[cf], acc[rf][cf], 0, 0, 0);
#pragma unroll
            for (int cf = 0; cf < 4; ++cf)
                acc[rf][cf] = __builtin_amdgcn_mfma_f32_16x16x32_bf16(
                    al, bh[cf], acc[rf][cf], 0, 0, 0);
        }
    }

    // epilogue: C layout col = lane&15, row = (lane>>4)*4 + r
#pragma unroll
    for (int rf = 0; rf < 4; ++rf) {
#pragma unroll
        for (int cf = 0; cf < 4; ++cf) {
            const int ocol = wv * 64 + cf * 16 + (lane & 15);
#pragma unroll
            for (int r = 0; r < 4; ++r) {
                const int orow = rf * 16 + (lane >> 4) * 4 + r;
                const int node = block0 + orow;
                float v2 = acc[rf][cf][r];
                if (wv == 0) {
                    v2 = fmaxf(v2 + bq[ocol], 0.f);
                    if (node < N) Qn[(size_t)node * 64 + ocol] = v2;
                } else if (wv == 1) {
                    const int ck = ocol - 64;
                    v2 = fmaxf(v2 + bk[ck], 0.f);
                    float vp = __shfl_xor(v2, 1);
                    if (node < N && !(lane & 1))
                        Kh[(size_t)node * 32 + (ck >> 1)] = pack_f16x2(v2, vp);
                } else {
                    const int cv = ocol - 128;
                    float vp = __shfl_xor(v2, 1);
                    if (node < N && !(lane & 1))
                        Vh[(size_t)node * 64 + (cv >> 1)] = pack_bf16x2(v2, vp);
                }
            }
        }
    }
}

// -------- aggregation: f16 Q/K via v_dot2, byte-offset gathers --------------
__global__ __launch_bounds__(256) void agg6(
    const int* __restrict__ deg_, const uint16_t* __restrict__ csr,
    const float* __restrict__ Qn, const uint32_t* __restrict__ Kh,
    const uint32_t* __restrict__ Vh, const float* __restrict__ bias,
    float* __restrict__ out, int N)
{
    __shared__ uint32_t qs[4][32];
    __shared__ float es[4][8][36];
    __shared__ int   cis[4][32];   // V row BYTE offsets (c << 8)

    const int wv = threadIdx.x >> 6;
    const int lane = threadIdx.x & 63;

    const int xcd = blockIdx.x & (NXCD - 1);
    const int nslice = (N + NXCD - 1) / NXCD;
    const int ln = (blockIdx.x >> 3) * 4 + wv;
    if (ln >= nslice) return;
    const int n = xcd * nslice + ln;
    if (n >= N) return;

    const int deg = min(deg_[n], CAP - 1);
    const int tot = deg + 1;   // + self-loop

    if (lane < 32) {
        float2 qq = reinterpret_cast<const float2*>(Qn + (size_t)n * 64)[lane];
        qs[wv][lane] = pack_f16x2(qq.x, qq.y);
    }
    __builtin_amdgcn_wave_barrier();

    const int e2 = lane >> 1;      // phase-A edge 0..31
    const int half = lane & 1;     // K half (heads 4*half..4*half+3)
    const int hrow = lane >> 3;    // phase-B head of feature pair 2*lane
    const float* esrow = &es[wv][hrow][0];
    const char* Kb = (const char*)Kh;
    const char* Vb = (const char*)Vh;
    const int lane4 = lane << 2;

    float accx = 0.f, accy = 0.f, accL = 0.f;

    for (int base = 0; base < tot; base += 32) {
        const int nn = min(32, tot - base);
        const int idxe = base + e2;
        const bool valide = (idxe < tot);
        int c = n;
        if (valide && idxe < deg) c = (int)csr[(size_t)n * CAP + idxe];
        if (!valide) c = 0;
        cis[wv][e2] = c << 8;   // both halves write same value

        const uint32_t koff = ((uint32_t)c << 7) + ((uint32_t)half << 6);
        const uint32_t* q16 = &qs[wv][half * 16];
#pragma unroll
        for (int hh = 0; hh < 4; ++hh) {
            uint4 kv = *reinterpret_cast<const uint4*>(Kb + koff + hh * 16);
            const uint32_t* q4 = q16 + hh * 4;
            float s = 0.f;
            s = __builtin_amdgcn_fdot2(as_h2(kv.x), as_h2(q4[0]), s, false);
            s = __builtin_amdgcn_fdot2(as_h2(kv.y), as_h2(q4[1]), s, false);
            s = __builtin_amdgcn_fdot2(as_h2(kv.z), as_h2(q4[2]), s, false);
            s = __builtin_amdgcn_fdot2(as_h2(kv.w), as_h2(q4[3]), s, false);
            es[wv][half * 4 + hh][e2] = valide ? __expf(s - SHIFT) : 0.f;
        }
        __builtin_amdgcn_wave_barrier();

        const int nn4 = (nn + 3) & ~3;
        for (int i = 0; i < nn4; i += 4) {
            int4 c4 = *reinterpret_cast<const int4*>(&cis[wv][i]);
            float4 e4 = *reinterpret_cast<const float4*>(&esrow[i]);
            uint32_t u0 = *reinterpret_cast<const uint32_t*>(Vb + (uint32_t)(c4.x + lane4));
            uint32_t u1 = *reinterpret_cast<const uint32_t*>(Vb + (uint32_t)(c4.y + lane4));
            uint32_t u2 = *reinterpret_cast<const uint32_t*>(Vb + (uint32_t)(c4.z + lane4));
            uint32_t u3 = *reinterpret_cast<const uint32_t*>(Vb + (uint32_t)(c4.w + lane4));
            accx += e4.x * __uint_as_float(u0 << 16);
            accy += e4.x * __uint_as_float(u0 & 0xFFFF0000u);
            accL += e4.x;
            accx += e4.y * __uint_as_float(u1 << 16);
            accy += e4.y * __uint_as_float(u1 & 0xFFFF0000u);
            accL += e4.y;
            accx += e4.z * __uint_as_float(u2 << 16);
            accy += e4.z * __uint_as_float(u2 & 0xFFFF0000u);
            accL += e4.z;
            accx += e4.w * __uint_as_float(u3 << 16);
            accy += e4.w * __uint_as_float(u3 & 0xFFFF0000u);
            accL += e4.w;
        }
        __builtin_amdgcn_wave_barrier();
    }

    float2 b = reinterpret_cast<const float2*>(bias)[lane];
    float inv = 1.0f / accL;
    float2 o;
    o.x = accx * inv + b.x;
    o.y = accy * inv + b.y;
    reinterpret_cast<float2*>(out)[(size_t)n * 64 + lane] = o;
}

extern "C" void kernel_launch(void* const* d_in, const int* in_sizes, int n_in,
                              void* d_out, int out_size, void* d_ws, size_t ws_size,
                              hipStream_t stream) {
    const float* x    = (const float*)d_in[0];
    const int*   ei   = (const int*)d_in[1];
    const float* Wq   = (const float*)d_in[2];
    const float* bq   = (const float*)d_in[3];
    const float* Wk   = (const float*)d_in[4];
    const float* bk   = (const float*)d_in[5];
    const float* Wv   = (const float*)d_in[6];
    const float* bias = (const float*)d_in[7];
    float* out = (float*)d_out;

    const int N = in_sizes[0] / 128;
    const int E = in_sizes[1] / 2;
    const int* row = ei;
    const int* col = ei + E;
    const int NB = (N + (1 << BSH) - 1) >> BSH;   // 128-node buckets

    // workspace layout (~44MB); csr u16 (N<=65535)
    float*    Qn     = (float*)d_ws;                       // N*64 f32
    uint32_t* Kh     = (uint32_t*)(Qn + (size_t)N * 64);   // N*32 u32 (f16x2)
    uint32_t* Vh     = Kh + (size_t)N * 32;                // N*64 u32 (bf16x2)
    uint32_t* Wh32   = Vh + (size_t)N * 64;                // 16384 u32
    uint32_t* Wl32   = Wh32 + 16384;                       // 16384 u32
    int*      deg    = (int*)(Wl32 + 16384);               // N
    int*      bcur   = deg + N;                            // 512
    uint32_t* inter  = (uint32_t*)(bcur + 512);            // NB*CAPB u32
    uint16_t* csr    = (uint16_t*)(inter + (size_t)NB * CAPB);  // N*CAP u16

    const int nslice = (N + NXCD - 1) / NXCD;
    const int agg_grid = ((nslice + 3) / 4) * NXCD;
    const int nl_grid = (N + 63) / 64;
    const int binA_grid = (E + ABSZ * AEPT - 1) / (ABSZ * AEPT);

    hipMemsetAsync(bcur, 0, 512 * sizeof(int), stream);
    prep_bin<<<PREP_BLKS + binA_grid, ABSZ, 0, stream>>>(
        Wq, Wk, Wv, Wh32, Wl32, row, col, bcur, inter, E);
    fused_nlb<<<NB + nl_grid, 256, 0, stream>>>(
        inter, bcur, csr, deg,
        x, (const uint16_t*)Wh32, (const uint16_t*)Wl32, bq, bk,
        Qn, Kh, Vh, N, NB);
    agg6<<<agg_grid, 256, 0, stream>>>(
        deg, csr, Qn, Kh, Vh, bias, out, N);
}